// Round 1
// baseline (459.842 us; speedup 1.0000x reference)
//
#include <hip/hip_runtime.h>
#include <stdint.h>

#define DEV __device__ __forceinline__

typedef __attribute__((ext_vector_type(8))) short short8;
typedef __attribute__((ext_vector_type(4))) float floatx4;

DEV ushort f2bf(float f) {
  union { float f; uint32_t u; } v; v.f = f;
  uint32_t u = v.u;
  return (ushort)((u + 0x7fffu + ((u >> 16) & 1u)) >> 16);
}

DEV floatx4 zero4() { floatx4 v; v[0] = 0.f; v[1] = 0.f; v[2] = 0.f; v[3] = 0.f; return v; }

// ---------------------------------------------------------------------------
// Cast kernel: x -> bf16, Wc/Wq/Wk/Wv -> bf16 (into concatenated W1=[Wc;Wq],
// W2=[Wk;Wv]), Wo -> bf16 with (qd,h)->(h,qd) column permutation.
// grid: 4096 blocks (x) + 5*256 blocks (weights); no early-outs.
// ---------------------------------------------------------------------------
__global__ __launch_bounds__(256) void cast_all(
    const float* __restrict__ x,
    const float* __restrict__ Wc, const float* __restrict__ Wq,
    const float* __restrict__ Wk, const float* __restrict__ Wv,
    const float* __restrict__ Wo,
    ushort* __restrict__ xb,
    ushort* __restrict__ Wcb, ushort* __restrict__ Wqb,
    ushort* __restrict__ Wkb, ushort* __restrict__ Wvb,
    ushort* __restrict__ Wob)
{
  const int bx = blockIdx.x;
  int y, i4;
  if (bx < 4096) { y = 0; i4 = bx * 256 + threadIdx.x; }
  else {
    int e = bx - 4096;
    y = 1 + (e >> 8);
    i4 = (e & 255) * 256 + threadIdx.x;
  }
  if (y == 0) {
    float4 v = ((const float4*)x)[i4];
    ushort4 o;
    o.x = f2bf(v.x); o.y = f2bf(v.y); o.z = f2bf(v.z); o.w = f2bf(v.w);
    *(ushort4*)&xb[i4 * 4] = o;
  } else if (y <= 4) {
    const float* s = (y == 1) ? Wc : (y == 2) ? Wq : (y == 3) ? Wk : Wv;
    ushort* d = (y == 1) ? Wcb : (y == 2) ? Wqb : (y == 3) ? Wkb : Wvb;
    float4 v = ((const float4*)s)[i4];
    ushort4 o;
    o.x = f2bf(v.x); o.y = f2bf(v.y); o.z = f2bf(v.z); o.w = f2bf(v.w);
    *(ushort4*)&d[i4 * 4] = o;
  } else {
    // Wob[o][h*64+qd] = Wo[o][qd*8+h]
    int base = i4 * 4;
    #pragma unroll
    for (int k = 0; k < 4; k++) {
      int e = base + k;
      int o = e >> 9;
      int hd = e & 511;
      int h = hd >> 6, qd = hd & 63;
      Wob[e] = f2bf(Wo[o * 512 + qd * 8 + h]);
    }
  }
}

// ---------------------------------------------------------------------------
// bf16 GEMM: C[M,N] = A[M,K=512] @ W[N,512]^T + bias.  128x128 tile, BK=64,
// 256 threads / 4 waves (2x2), each wave 64x64 via 4x4 MFMAs (16x16x32).
// Linear LDS [128][64] with XOR swizzle (slot ^= row&7): conflict-free
// b128 fragment reads; staging pre-swizzles the global column slot.
// grid (M/128, N/128): blockIdx.x = row-tile so XCD round-robin keeps each
// A row-panel on one XCD (W is small and L2-resident everywhere).
// ---------------------------------------------------------------------------
template <typename OutT>
__global__ __launch_bounds__(256) void gemm_bias(
    const ushort* __restrict__ A, int lda,
    const ushort* __restrict__ W,
    const float* __restrict__ bias0, const float* __restrict__ bias1,
    OutT* __restrict__ C, int ldc)
{
  __shared__ __align__(16) ushort As[128 * 64];
  __shared__ __align__(16) ushort Bs[128 * 64];

  const int t = threadIdx.x;
  const int lane = t & 63;
  const int ln = lane & 15, q = lane >> 4;
  const int w = t >> 6;
  const int wm = w >> 1, wn = w & 1;
  const int row0 = blockIdx.x * 128, col0 = blockIdx.y * 128;

  floatx4 acc[4][4];
  #pragma unroll
  for (int i = 0; i < 4; i++)
    #pragma unroll
    for (int j = 0; j < 4; j++) acc[i][j] = zero4();

  const char* asb = (const char*)As;
  const char* bsb = (const char*)Bs;

  for (int k0 = 0; k0 < 512; k0 += 64) {
    #pragma unroll
    for (int i = 0; i < 4; i++) {
      int L = i * 256 + t;
      int r = L >> 3, s = L & 7;
      int sg = s ^ (r & 7);  // pre-swizzled source slot
      *(short8*)&As[L * 8] = *(const short8*)&A[(size_t)(row0 + r) * lda + k0 + sg * 8];
      *(short8*)&Bs[L * 8] = *(const short8*)&W[(size_t)(col0 + r) * 512 + k0 + sg * 8];
    }
    __syncthreads();
    #pragma unroll
    for (int kk = 0; kk < 2; kk++) {
      short8 af[4], bf[4];
      #pragma unroll
      for (int mi = 0; mi < 4; mi++) {
        int row = wm * 64 + mi * 16 + ln;
        af[mi] = *(const short8*)(asb + ((row * 128 + kk * 64 + q * 16) ^ ((row & 7) << 4)));
      }
      #pragma unroll
      for (int ni = 0; ni < 4; ni++) {
        int row = wn * 64 + ni * 16 + ln;
        bf[ni] = *(const short8*)(bsb + ((row * 128 + kk * 64 + q * 16) ^ ((row & 7) << 4)));
      }
      #pragma unroll
      for (int mi = 0; mi < 4; mi++)
        #pragma unroll
        for (int ni = 0; ni < 4; ni++)
          acc[mi][ni] = __builtin_amdgcn_mfma_f32_16x16x32_bf16(
              af[mi], bf[ni], acc[mi][ni], 0, 0, 0);
    }
    __syncthreads();
  }

  #pragma unroll
  for (int mi = 0; mi < 4; mi++)
    #pragma unroll
    for (int ni = 0; ni < 4; ni++) {
      int gcol = col0 + wn * 64 + ni * 16 + ln;
      float bv = (gcol < 512) ? bias0[gcol] : bias1[gcol - 512];
      #pragma unroll
      for (int r = 0; r < 4; r++) {
        int grow = row0 + wm * 64 + mi * 16 + q * 4 + r;
        float val = acc[mi][ni][r] + bv;
        if constexpr (sizeof(OutT) == 2) {
          C[(size_t)grow * ldc + gcol] = (OutT)f2bf(val);
        } else {
          C[(size_t)grow * ldc + gcol] = (OutT)val;
        }
      }
    }
}

// ---------------------------------------------------------------------------
// V transpose: Vt[pair][d][l] <- KV[b*1024+l][512 + h*64 + d]
// grid (16 ltiles, 64 pairs) x 256
// ---------------------------------------------------------------------------
__global__ __launch_bounds__(256) void vtrans(
    const ushort* __restrict__ KV, ushort* __restrict__ Vt)
{
  __shared__ __align__(16) ushort Ts[64 * 72];
  const int t = threadIdx.x;
  const int lt = blockIdx.x, pair = blockIdx.y;
  const int b = pair >> 3, h = pair & 7;
  #pragma unroll
  for (int i = 0; i < 2; i++) {
    int e = t + i * 256;
    int r = e >> 3, s = e & 7;
    *(short8*)&Ts[r * 72 + s * 8] =
        *(const short8*)&KV[((size_t)b * 1024 + lt * 64 + r) * 1024 + 512 + h * 64 + s * 8];
  }
  __syncthreads();
  #pragma unroll
  for (int i = 0; i < 2; i++) {
    int e = t + i * 256;
    int d = e >> 3, s = e & 7;
    short8 o;
    #pragma unroll
    for (int k = 0; k < 8; k++) o[k] = (short)Ts[(s * 8 + k) * 72 + d];
    *(short8*)&Vt[((size_t)pair * 64 + d) * 1024 + lt * 64 + s * 8] = o;
  }
}

// ---------------------------------------------------------------------------
// Fused attention. Block = 32 Q rows x one (b,h); 512 threads = 8 waves as
// 2 row-groups (wr) x 4 col-groups (wc).
// Phase 1 (barrier-free): QK^T with K B-fragments loaded DIRECTLY from
//   global (L2-resident, contiguous 16B per lane) -> S[16] tiles in regs.
// Softmax: in-wave shfl + 2 cross-wave LDS rounds.
// Phase 2: scores (f32) written straight from regs (nontemporal);
//   P (bf16) written once to a XOR-swizzled Ps[32][1024]; one barrier; PV
//   with A-frags from Ps (conflict-free b128) and V-frags DIRECTLY from
//   global Vt. 3 barriers total per block.
// grid (64 pairs, 32 row-tiles): pair on blockIdx.x so each (b,h)'s K/Vt
// stays on one XCD's L2.
// ---------------------------------------------------------------------------
__global__ __launch_bounds__(512) void attn(
    const ushort* __restrict__ XQ,   // [8192][1024], Q at cols 512+h*64
    const ushort* __restrict__ KV,   // [8192][1024], K at cols h*64
    const ushort* __restrict__ Vt,   // [64 pairs][64 d][1024 l]
    float* __restrict__ scores,
    ushort* __restrict__ Ab)         // [8192][512] merged (h,d)
{
  __shared__ __align__(16) ushort Ps[32 * 1024];  // 64 KB, XOR-swizzled
  __shared__ float sm[128];
  __shared__ float sl[128];

  const int t = threadIdx.x;
  const int lane = t & 63, w = t >> 6;
  const int ln = lane & 15, q = lane >> 4;
  const int wr = w >> 2, wc = w & 3;
  const int pair = blockIdx.x, rt = blockIdx.y;
  const int b = pair >> 3, h = pair & 7;
  const int l0 = rt * 32;
  const size_t bRow = (size_t)b * 1024;

  // ---- Q fragments direct from global ----
  const ushort* qrow = &XQ[(bRow + l0 + wr * 16 + ln) * 1024 + 512 + h * 64];
  short8 a0 = *(const short8*)&qrow[q * 8];        // d 0..31
  short8 a1 = *(const short8*)&qrow[32 + q * 8];   // d 32..63

  // ---- QK^T: tile ct covers cols ct*64 + wc*16 + [0,16) ----
  floatx4 S[16];
  #pragma unroll
  for (int i = 0; i < 16; i++) S[i] = zero4();

  const ushort* krow = &KV[(bRow + wc * 16 + ln) * 1024 + h * 64];
  #pragma unroll
  for (int ct = 0; ct < 16; ct++) {
    const ushort* kp = krow + (size_t)ct * 64 * 1024;
    short8 b0 = *(const short8*)&kp[q * 8];
    short8 b1 = *(const short8*)&kp[32 + q * 8];
    S[ct] = __builtin_amdgcn_mfma_f32_16x16x32_bf16(a0, b0, S[ct], 0, 0, 0);
    S[ct] = __builtin_amdgcn_mfma_f32_16x16x32_bf16(a1, b1, S[ct], 0, 0, 0);
  }

  // ---- softmax (rows q*4+r within row-group wr) ----
  float mr[4];
  #pragma unroll
  for (int r = 0; r < 4; r++) {
    float m = -3.4e38f;
    #pragma unroll
    for (int ct = 0; ct < 16; ct++) m = fmaxf(m, S[ct][r]);
    #pragma unroll
    for (int off = 1; off < 16; off <<= 1) m = fmaxf(m, __shfl_xor(m, off));
    mr[r] = m;
  }
  if (ln == 0) {
    #pragma unroll
    for (int r = 0; r < 4; r++) sm[wr * 64 + wc * 16 + q * 4 + r] = mr[r];
  }
  __syncthreads();
  float mfull[4], lsum[4];
  #pragma unroll
  for (int r = 0; r < 4; r++) {
    int base = wr * 64 + q * 4 + r;
    mfull[r] = fmaxf(fmaxf(sm[base], sm[base + 16]),
                     fmaxf(sm[base + 32], sm[base + 48]));
    lsum[r] = 0.0f;
  }
  #pragma unroll
  for (int ct = 0; ct < 16; ct++)
    #pragma unroll
    for (int r = 0; r < 4; r++) {
      float e = __expf((S[ct][r] - mfull[r]) * 0.125f);
      S[ct][r] = e;
      lsum[r] += e;
    }
  #pragma unroll
  for (int r = 0; r < 4; r++) {
    #pragma unroll
    for (int off = 1; off < 16; off <<= 1) lsum[r] += __shfl_xor(lsum[r], off);
  }
  if (ln == 0) {
    #pragma unroll
    for (int r = 0; r < 4; r++) sl[wr * 64 + wc * 16 + q * 4 + r] = lsum[r];
  }
  __syncthreads();
  float rl[4];
  #pragma unroll
  for (int r = 0; r < 4; r++) {
    int base = wr * 64 + q * 4 + r;
    rl[r] = 1.0f / (sl[base] + sl[base + 16] + sl[base + 32] + sl[base + 48]);
  }

  // ---- scores (f32, direct from regs, nontemporal) + Ps (bf16, swizzled) ----
  char* psb = (char*)Ps;
  #pragma unroll
  for (int ct = 0; ct < 16; ct++) {
    int col = ct * 64 + wc * 16 + ln;
    #pragma unroll
    for (int r = 0; r < 4; r++) {
      int row = wr * 16 + q * 4 + r;
      float p = S[ct][r] * rl[r];
      __builtin_nontemporal_store(
          p, &scores[((size_t)pair * 1024 + l0 + row) * 1024 + col]);
      *(ushort*)(psb + (((row * 1024 + col) * 2) ^ ((row & 7) << 4))) = f2bf(p);
    }
  }
  __syncthreads();

  // ---- PV: A from Ps (swizzled b128, conflict-free), B direct from Vt ----
  floatx4 O0 = zero4(), O1 = zero4();
  const int arow = wr * 16 + ln;
  const int aswz = (arow & 7) << 4;
  const char* pa = psb + arow * 2048;
  const ushort* vrow = &Vt[((size_t)pair * 64 + wc * 16 + ln) * 1024];
  #pragma unroll
  for (int kc2 = 0; kc2 < 16; kc2++) {
    int k0 = kc2 * 2;
    short8 af0 = *(const short8*)(pa + ((k0 * 64 + q * 16) ^ aswz));
    short8 bv0 = *(const short8*)&vrow[k0 * 32 + q * 8];
    O0 = __builtin_amdgcn_mfma_f32_16x16x32_bf16(af0, bv0, O0, 0, 0, 0);
    short8 af1 = *(const short8*)(pa + (((k0 + 1) * 64 + q * 16) ^ aswz));
    short8 bv1 = *(const short8*)&vrow[(k0 + 1) * 32 + q * 8];
    O1 = __builtin_amdgcn_mfma_f32_16x16x32_bf16(af1, bv1, O1, 0, 0, 0);
  }

  // ---- store merged[b, l, h*64 + d] ----
  #pragma unroll
  for (int r = 0; r < 4; r++) {
    float o = O0[r] + O1[r];
    Ab[(bRow + l0 + wr * 16 + q * 4 + r) * 512 + h * 64 + wc * 16 + ln] = f2bf(o);
  }
}

// ---------------------------------------------------------------------------
extern "C" void kernel_launch(void* const* d_in, const int* in_sizes, int n_in,
                              void* d_out, int out_size, void* d_ws, size_t ws_size,
                              hipStream_t stream)
{
  const float* x  = (const float*)d_in[0];
  const float* Wc = (const float*)d_in[1];
  const float* bc = (const float*)d_in[2];
  const float* Wq = (const float*)d_in[3];
  const float* bq = (const float*)d_in[4];
  const float* Wk = (const float*)d_in[5];
  const float* bk = (const float*)d_in[6];
  const float* Wv = (const float*)d_in[7];
  const float* bv = (const float*)d_in[8];
  const float* Wo = (const float*)d_in[9];
  const float* bo = (const float*)d_in[10];

  float* out = (float*)d_out;                       // [8,1024,512]
  float* scores = out + (size_t)8 * 1024 * 512;     // [8,8,1024,1024]

  char* ws = (char*)d_ws;
  const size_t MB = (size_t)1 << 20;
  ushort* xb  = (ushort*)(ws + 0);           // 8 MB, reused as Ab after G1
  ushort* Ab  = xb;
  ushort* XQ  = (ushort*)(ws + 8 * MB);      // 16 MB: [8192][1024] = x_r | Q
  ushort* KV  = (ushort*)(ws + 24 * MB);     // 16 MB: [8192][1024] = K | V
  ushort* Vt  = (ushort*)(ws + 40 * MB);     // 8 MB: [64][64][1024]
  ushort* W1  = (ushort*)(ws + 48 * MB);     // 1 MB: [Wc;Wq] bf16
  ushort* W2  = (ushort*)(ws + 49 * MB);     // 1 MB: [Wk;Wv] bf16
  ushort* Wob = (ushort*)(ws + 50 * MB);     // 0.5 MB

  cast_all<<<dim3(4096 + 5 * 256), 256, 0, stream>>>(
      x, Wc, Wq, Wk, Wv, Wo,
      xb, W1, W1 + 262144, W2, W2 + 262144, Wob);

  // G1: [x_r | Q] = xb @ [Wc;Wq]^T
  gemm_bias<ushort><<<dim3(64, 8), 256, 0, stream>>>(
      xb, 512, W1, bc, bq, XQ, 1024);
  // G2: [K | V] = x_r @ [Wk;Wv]^T
  gemm_bias<ushort><<<dim3(64, 8), 256, 0, stream>>>(
      XQ, 1024, W2, bk, bv, KV, 1024);

  vtrans<<<dim3(16, 64), 256, 0, stream>>>(KV, Vt);

  attn<<<dim3(64, 32), 512, 0, stream>>>(XQ, KV, Vt, scores, Ab);

  // G3: out = merged @ Wob^T
  gemm_bias<float><<<dim3(64, 4), 256, 0, stream>>>(
      Ab, 512, Wob, bo, bo, out, 512);
}